// Round 10
// baseline (730.235 us; speedup 1.0000x reference)
//
#include <hip/hip_runtime.h>
#include <hip/hip_bf16.h>

#define N_NODES 100000
#define N_FEAT  1433
#define NKT1    46       // k-tiles of 32 for K=1433->1472
#define HID     64
#define NCLS    7
#define SCAN_BLK 1024
#define NBLK    ((N_NODES + SCAN_BLK - 1) / SCAN_BLK)   // 98

typedef __attribute__((ext_vector_type(8))) short short8v;
typedef __attribute__((ext_vector_type(4))) float f32x4;

__device__ __forceinline__ unsigned short f2bf(float v) {
    unsigned u = __float_as_uint(v);
    unsigned r = (u + 0x7FFFu + ((u >> 16) & 1u)) >> 16;   // RNE
    return (unsigned short)r;
}
__device__ __forceinline__ float bf2f(unsigned short h) {
    return __uint_as_float(((unsigned)h) << 16);
}

// packed f32x2 -> bf16x2 via v_cvt_pk_bf16_f32 (RNE), compiler-scheduled
__device__ __forceinline__ unsigned pk2(float a, float b) {
    union { __hip_bfloat162 h2; unsigned u; } cv;
    cv.h2 = __float22bfloat162_rn(make_float2(a, b));
    return cv.u;
}
__device__ __forceinline__ short8v cvt8(const float* v) {
    union { unsigned u[4]; short8v s; } r;
#pragma unroll
    for (int i = 0; i < 4; ++i) r.u[i] = pk2(v[2 * i], v[2 * i + 1]);
    return r.s;
}

// ---------------- degree histogram ----------------
__global__ __launch_bounds__(256)
void hist_kernel(const int* __restrict__ dst, int* __restrict__ counts, int E) {
    int e = blockIdx.x * 256 + threadIdx.x;
    if (e < E) atomicAdd(&counts[dst[e]], 1);
}

__global__ __launch_bounds__(256)
void dinv_kernel(const int* __restrict__ counts, float* __restrict__ dinv, int n) {
    int i = blockIdx.x * 256 + threadIdx.x;
    if (i < n) dinv[i] = rsqrtf((float)(counts[i] + 1));   // +1 = self loop
}

// ---------------- 3-phase parallel exclusive scan ----------------
__global__ __launch_bounds__(SCAN_BLK)
void scan_p1(const int* __restrict__ counts, int* __restrict__ local_ex,
             int* __restrict__ blocksum, int n) {
    __shared__ int sh[SCAN_BLK];
    int t = threadIdx.x;
    int i = blockIdx.x * SCAN_BLK + t;
    int v = (i < n) ? counts[i] : 0;
    sh[t] = v;
    __syncthreads();
    for (int off = 1; off < SCAN_BLK; off <<= 1) {
        int u = (t >= off) ? sh[t - off] : 0;
        __syncthreads();
        sh[t] += u;
        __syncthreads();
    }
    if (i < n) local_ex[i] = sh[t] - v;      // exclusive
    if (t == SCAN_BLK - 1) blocksum[blockIdx.x] = sh[t];
}

__global__ __launch_bounds__(128)
void scan_p2(int* __restrict__ blocksum, int* __restrict__ blockoff,
             int* __restrict__ offsets_last, int nb) {
    __shared__ int sh[128];
    int t = threadIdx.x;
    int v = (t < nb) ? blocksum[t] : 0;
    sh[t] = v;
    __syncthreads();
    for (int off = 1; off < 128; off <<= 1) {
        int u = (t >= off) ? sh[t - off] : 0;
        __syncthreads();
        sh[t] += u;
        __syncthreads();
    }
    if (t < nb) blockoff[t] = sh[t] - v;
    if (t == nb - 1) *offsets_last = sh[t];
}

__global__ __launch_bounds__(SCAN_BLK)
void scan_p3(const int* __restrict__ local_ex, const int* __restrict__ blockoff,
             int* __restrict__ offsets, int* __restrict__ cursor, int n) {
    int i = blockIdx.x * SCAN_BLK + threadIdx.x;
    if (i < n) {
        int v = local_ex[i] + blockoff[blockIdx.x];
        offsets[i] = v;
        cursor[i]  = v;
    }
}

// ---------------- CSR scatter: single int2 payload (src, weight) ----------------
__global__ __launch_bounds__(256)
void scatter_kernel(const int* __restrict__ src, const int* __restrict__ dst,
                    const float* __restrict__ dinv, int* __restrict__ cursor,
                    int2* __restrict__ pay, int E) {
    int e = blockIdx.x * 256 + threadIdx.x;
    if (e >= E) return;
    int s = src[e], d = dst[e];
    int pos = atomicAdd(&cursor[d], 1);
    pay[pos] = make_int2(s, __float_as_int(dinv[s] * dinv[d]));
}

// ---------------- generic W -> fragment-major bf16 hi/lo ----------------
__global__ __launch_bounds__(256)
void convert_wfrag_g(const float* __restrict__ W, int K, int ncols, int nkt, int nfc,
                     unsigned short* __restrict__ wfh, unsigned short* __restrict__ wfl) {
    int tid = blockIdx.x * 256 + threadIdx.x;
    if (tid >= nkt * nfc * 64) return;
    int kt   = tid / (nfc * 64);
    int rem  = tid % (nfc * 64);
    int nf   = rem >> 6;
    int lane = rem & 63;
    int n  = nf * 16 + (lane & 15);
    int kb = kt * 32 + ((lane >> 4) << 3);
    short8v hi, lo;
#pragma unroll
    for (int j = 0; j < 8; ++j) {
        int k = kb + j;
        float v = (k < K && n < ncols) ? W[(size_t)k * ncols + n] : 0.f;
        unsigned short h = f2bf(v);
        hi[j] = (short)h;
        lo[j] = (short)f2bf(v - bf2f(h));
    }
    *(short8v*)(wfh + (size_t)tid * 8) = hi;
    *(short8v*)(wfl + (size_t)tid * 8) = lo;
}

// masked tail fragment load (executes once per kernel)
__device__ __forceinline__ short8v load_frag_f32(const float* __restrict__ row, int kk) {
    float v[8];
#pragma unroll
    for (int j = 0; j < 8; ++j) v[j] = (kk + j < N_FEAT) ? row[kk + j] : 0.f;
    return cvt8(v);
}

// ---------------- GEMM1 v9: explicit 1-deep register prefetch pipeline ----------------
// Grid-limited to ~3 blocks/CU, so VGPRs to ~128 are free: __launch_bounds__(256,2).
__global__ __launch_bounds__(256, 2)
void gemm_xw_v9(const float* __restrict__ X,
                const unsigned short* __restrict__ wfh,
                unsigned short* __restrict__ H16, int M) {
    const int t    = threadIdx.x;
    const int lane = t & 63;
    const int w    = t >> 6;
    const int m0   = blockIdx.x * 128 + w * 32;
    const int lrow = lane & 15;
    const int koff = (lane >> 4) * 8;

    f32x4 acc[2][4];
#pragma unroll
    for (int i = 0; i < 2; ++i)
#pragma unroll
        for (int j = 0; j < 4; ++j) acc[i][j] = (f32x4){0.f, 0.f, 0.f, 0.f};

    const float* a0 = X + (size_t)min(m0 + lrow,      M - 1) * N_FEAT + koff;
    const float* a1 = X + (size_t)min(m0 + 16 + lrow, M - 1) * N_FEAT + koff;
    const short8v* bh = (const short8v*)wfh + lane;   // + (kt*4+nf)*64

    // prologue: load kt=0 into current buffers
    float   c0[8], c1[8];
    short8v bC[4];
    __builtin_memcpy(c0, a0, 32);
    __builtin_memcpy(c1, a1, 32);
#pragma unroll
    for (int nf = 0; nf < 4; ++nf) bC[nf] = bh[nf * 64];

    // main pipeline: compute kt, prefetch kt+1 (kt = 0..42)
#pragma unroll 2
    for (int kt = 0; kt < 43; ++kt) {
        float   n0[8], n1[8];
        short8v bN[4];
        __builtin_memcpy(n0, a0 + (kt + 1) * 32, 32);     // issue next-tile loads FIRST
        __builtin_memcpy(n1, a1 + (kt + 1) * 32, 32);
#pragma unroll
        for (int nf = 0; nf < 4; ++nf) bN[nf] = bh[((kt + 1) * 4 + nf) * 64];

        short8v aH0 = cvt8(c0), aH1 = cvt8(c1);
#pragma unroll
        for (int nf = 0; nf < 4; ++nf) {
            acc[0][nf] = __builtin_amdgcn_mfma_f32_16x16x32_bf16(aH0, bC[nf], acc[0][nf], 0, 0, 0);
            acc[1][nf] = __builtin_amdgcn_mfma_f32_16x16x32_bf16(aH1, bC[nf], acc[1][nf], 0, 0, 0);
        }
        // rotate (register-renamed under unroll)
#pragma unroll
        for (int j = 0; j < 8; ++j) { c0[j] = n0[j]; c1[j] = n1[j]; }
#pragma unroll
        for (int nf = 0; nf < 4; ++nf) bC[nf] = bN[nf];
    }
    {   // kt = 43 (already in c/bC)
        short8v aH0 = cvt8(c0), aH1 = cvt8(c1);
#pragma unroll
        for (int nf = 0; nf < 4; ++nf) {
            acc[0][nf] = __builtin_amdgcn_mfma_f32_16x16x32_bf16(aH0, bC[nf], acc[0][nf], 0, 0, 0);
            acc[1][nf] = __builtin_amdgcn_mfma_f32_16x16x32_bf16(aH1, bC[nf], acc[1][nf], 0, 0, 0);
        }
    }
    {   // tail kt = 44 (k 1408..1439, masked >= 1433)
        const int kt = 44;
        int kk = kt * 32;
        short8v aH0 = load_frag_f32(a0 - koff, kk + koff);
        short8v aH1 = load_frag_f32(a1 - koff, kk + koff);
#pragma unroll
        for (int nf = 0; nf < 4; ++nf) {
            short8v bT = bh[(kt * 4 + nf) * 64];
            acc[0][nf] = __builtin_amdgcn_mfma_f32_16x16x32_bf16(aH0, bT, acc[0][nf], 0, 0, 0);
            acc[1][nf] = __builtin_amdgcn_mfma_f32_16x16x32_bf16(aH1, bT, acc[1][nf], 0, 0, 0);
        }
    }
    // C: col = lane&15, row = (lane>>4)*4 + reg
#pragma unroll
    for (int mf = 0; mf < 2; ++mf)
#pragma unroll
        for (int r = 0; r < 4; ++r) {
            int row = m0 + mf * 16 + ((lane >> 4) << 2) + r;
            if (row < M) {
#pragma unroll
                for (int nf = 0; nf < 4; ++nf)
                    H16[(size_t)row * 64 + nf * 16 + lrow] = f2bf(acc[mf][nf][r]);
            }
        }
}

// ---------------- GEMM2 v3: [M,64] f32 @ [64,64], cvt_pk, frag-major W2 hi/lo ----------------
__global__ __launch_bounds__(256)
void gemm_hid_v3(const float* __restrict__ A,
                 const unsigned short* __restrict__ wfh,
                 const unsigned short* __restrict__ wfl,
                 unsigned short* __restrict__ H16, int M) {
    const int t    = threadIdx.x;
    const int lane = t & 63;
    const int w    = t >> 6;
    const int m0   = blockIdx.x * 128 + w * 32;
    const int lrow = lane & 15;
    const int koff = (lane >> 4) * 8;

    f32x4 acc[2][4];
#pragma unroll
    for (int i = 0; i < 2; ++i)
#pragma unroll
        for (int j = 0; j < 4; ++j) acc[i][j] = (f32x4){0.f, 0.f, 0.f, 0.f};

    const float* a0 = A + (size_t)min(m0 + lrow,      M - 1) * 64;
    const float* a1 = A + (size_t)min(m0 + 16 + lrow, M - 1) * 64;
    const short8v* bh = (const short8v*)wfh + lane;
    const short8v* bl = (const short8v*)wfl + lane;

#pragma unroll
    for (int kt = 0; kt < 2; ++kt) {
        int kk = kt * 32 + koff;
        short8v aH[2], bH[4], bL[4];
        float v0[8], v1[8];
        __builtin_memcpy(v0, a0 + kk, 32);
        __builtin_memcpy(v1, a1 + kk, 32);
        aH[0] = cvt8(v0);
        aH[1] = cvt8(v1);
#pragma unroll
        for (int nf = 0; nf < 4; ++nf) {
            bH[nf] = bh[(kt * 4 + nf) * 64];
            bL[nf] = bl[(kt * 4 + nf) * 64];
        }
#pragma unroll
        for (int mf = 0; mf < 2; ++mf)
#pragma unroll
            for (int nf = 0; nf < 4; ++nf) {
                acc[mf][nf] = __builtin_amdgcn_mfma_f32_16x16x32_bf16(aH[mf], bH[nf], acc[mf][nf], 0, 0, 0);
                acc[mf][nf] = __builtin_amdgcn_mfma_f32_16x16x32_bf16(aH[mf], bL[nf], acc[mf][nf], 0, 0, 0);
            }
    }
#pragma unroll
    for (int mf = 0; mf < 2; ++mf)
#pragma unroll
        for (int r = 0; r < 4; ++r) {
            int row = m0 + mf * 16 + ((lane >> 4) << 2) + r;
            if (row < M) {
#pragma unroll
                for (int nf = 0; nf < 4; ++nf)
                    H16[(size_t)row * 64 + nf * 16 + lrow] = f2bf(acc[mf][nf][r]);
            }
        }
}

// ---------------- aggregate v4: 8 edges/iter, 2 gathers in flight ----------------
__global__ __launch_bounds__(256)
void aggregate_v4(const unsigned short* __restrict__ h16, const int2* __restrict__ pay,
                  const int* __restrict__ offsets,
                  const float* __restrict__ dinv, const float* __restrict__ bias,
                  float* __restrict__ out, int n) {
    int wid  = (blockIdx.x * blockDim.x + threadIdx.x) >> 6;
    int lane = threadIdx.x & 63;
    if (wid >= n) return;
    const int g  = lane >> 4;          // edge subgroup 0..3
    const int f4 = (lane & 15) * 4;    // feature base

    float a0 = 0.f, a1 = 0.f, a2 = 0.f, a3 = 0.f;
    int beg = offsets[wid], end = offsets[wid + 1];
    int cnt = end - beg;
    int nq  = cnt >> 3;
    int e   = beg + g;
#pragma unroll 2
    for (int q = 0; q < nq; ++q, e += 8) {
        int2 p1 = pay[e];
        int2 p2 = pay[e + 4];
        float w1 = __int_as_float(p1.y);
        float w2 = __int_as_float(p2.y);
        ushort4 h1 = *(const ushort4*)(h16 + (size_t)p1.x * HID + f4);
        ushort4 h2 = *(const ushort4*)(h16 + (size_t)p2.x * HID + f4);
        a0 = fmaf(bf2f(h1.x), w1, a0); a1 = fmaf(bf2f(h1.y), w1, a1);
        a2 = fmaf(bf2f(h1.z), w1, a2); a3 = fmaf(bf2f(h1.w), w1, a3);
        a0 = fmaf(bf2f(h2.x), w2, a0); a1 = fmaf(bf2f(h2.y), w2, a1);
        a2 = fmaf(bf2f(h2.z), w2, a2); a3 = fmaf(bf2f(h2.w), w2, a3);
    }
    int rem  = cnt & 7;
    int base = beg + nq * 8;
    if (g < rem) {
        int2  pw  = pay[base + g];
        float wgt = __int_as_float(pw.y);
        ushort4 hv = *(const ushort4*)(h16 + (size_t)pw.x * HID + f4);
        a0 = fmaf(bf2f(hv.x), wgt, a0); a1 = fmaf(bf2f(hv.y), wgt, a1);
        a2 = fmaf(bf2f(hv.z), wgt, a2); a3 = fmaf(bf2f(hv.w), wgt, a3);
    }
    if (g + 4 < rem) {
        int2  pw  = pay[base + g + 4];
        float wgt = __int_as_float(pw.y);
        ushort4 hv = *(const ushort4*)(h16 + (size_t)pw.x * HID + f4);
        a0 = fmaf(bf2f(hv.x), wgt, a0); a1 = fmaf(bf2f(hv.y), wgt, a1);
        a2 = fmaf(bf2f(hv.z), wgt, a2); a3 = fmaf(bf2f(hv.w), wgt, a3);
    }
    if (g == 0) {   // self loop
        float di = dinv[wid];
        float w2 = di * di;
        ushort4 hv = *(const ushort4*)(h16 + (size_t)wid * HID + f4);
        a0 = fmaf(bf2f(hv.x), w2, a0); a1 = fmaf(bf2f(hv.y), w2, a1);
        a2 = fmaf(bf2f(hv.z), w2, a2); a3 = fmaf(bf2f(hv.w), w2, a3);
    }
    a0 += __shfl_xor(a0, 16); a0 += __shfl_xor(a0, 32);
    a1 += __shfl_xor(a1, 16); a1 += __shfl_xor(a1, 32);
    a2 += __shfl_xor(a2, 16); a2 += __shfl_xor(a2, 32);
    a3 += __shfl_xor(a3, 16); a3 += __shfl_xor(a3, 32);
    if (g == 0) {
        float4 bv = *(const float4*)&bias[f4];
        float4 o;
        o.x = fmaxf(a0 + bv.x, 0.f);
        o.y = fmaxf(a1 + bv.y, 0.f);
        o.z = fmaxf(a2 + bv.z, 0.f);
        o.w = fmaxf(a3 + bv.w, 0.f);
        *(float4*)&out[(size_t)wid * HID + f4] = o;
    }
}

// ---------------- fused MLP head via MFMA + butterfly log_softmax ----------------
__device__ __forceinline__ void split8(const float* v, short8v& h, short8v& l) {
    h = cvt8(v);
    float res[8];
#pragma unroll
    for (int j = 0; j < 8; ++j) res[j] = v[j] - bf2f((unsigned short)h[j]);
    l = cvt8(res);
}

__global__ __launch_bounds__(256)
void mlp_mfma(const float* __restrict__ y,
              const unsigned short* __restrict__ w1h, const unsigned short* __restrict__ w1l,
              const unsigned short* __restrict__ w2h, const unsigned short* __restrict__ w2l,
              const unsigned short* __restrict__ w3h, const unsigned short* __restrict__ w3l,
              const float* __restrict__ bf1, const float* __restrict__ bf2,
              const float* __restrict__ bf3,
              float* __restrict__ out, int M) {
    __shared__ float tbuf[4][32 * 64];
    const int t    = threadIdx.x;
    const int lane = t & 63;
    const int w    = t >> 6;
    const int m0   = blockIdx.x * 128 + w * 32;
    const int lrow = lane & 15;
    const int hi16 = lane >> 4;
    const int koff = hi16 * 8;
    float* tb = tbuf[w];

    float b1v[4], b2v[4];
#pragma unroll
    for (int nf = 0; nf < 4; ++nf) {
        b1v[nf] = bf1[nf * 16 + lrow];
        b2v[nf] = bf2[nf * 16 + lrow];
    }
    float b3v = (lrow < NCLS) ? bf3[lrow] : 0.f;

    short8v aH[2][2], aL[2][2];   // [mf][kt]
    {
        const float* a0 = y + (size_t)min(m0 + lrow,      M - 1) * 64;
        const float* a1 = y + (size_t)min(m0 + 16 + lrow, M - 1) * 64;
#pragma unroll
        for (int kt = 0; kt < 2; ++kt) {
            float v0[8], v1[8];
            __builtin_memcpy(v0, a0 + kt * 32 + koff, 32);
            __builtin_memcpy(v1, a1 + kt * 32 + koff, 32);
            split8(v0, aH[0][kt], aL[0][kt]);
            split8(v1, aH[1][kt], aL[1][kt]);
        }
    }

#pragma unroll
    for (int layer = 0; layer < 2; ++layer) {
        const unsigned short* wh = layer ? w2h : w1h;
        const unsigned short* wl = layer ? w2l : w1l;
        const float* bv = layer ? b2v : b1v;
        f32x4 acc[2][4];
#pragma unroll
        for (int i = 0; i < 2; ++i)
#pragma unroll
            for (int j = 0; j < 4; ++j) acc[i][j] = (f32x4){0.f, 0.f, 0.f, 0.f};
#pragma unroll
        for (int kt = 0; kt < 2; ++kt) {
            short8v bH[4], bL[4];
#pragma unroll
            for (int nf = 0; nf < 4; ++nf) {
                bH[nf] = *((const short8v*)wh + (kt * 4 + nf) * 64 + lane);
                bL[nf] = *((const short8v*)wl + (kt * 4 + nf) * 64 + lane);
            }
#pragma unroll
            for (int mf = 0; mf < 2; ++mf)
#pragma unroll
                for (int nf = 0; nf < 4; ++nf) {
                    acc[mf][nf] = __builtin_amdgcn_mfma_f32_16x16x32_bf16(aH[mf][kt], bH[nf], acc[mf][nf], 0, 0, 0);
                    acc[mf][nf] = __builtin_amdgcn_mfma_f32_16x16x32_bf16(aH[mf][kt], bL[nf], acc[mf][nf], 0, 0, 0);
                    acc[mf][nf] = __builtin_amdgcn_mfma_f32_16x16x32_bf16(aL[mf][kt], bH[nf], acc[mf][nf], 0, 0, 0);
                }
        }
#pragma unroll
        for (int mf = 0; mf < 2; ++mf)
#pragma unroll
            for (int nf = 0; nf < 4; ++nf)
#pragma unroll
                for (int r = 0; r < 4; ++r) {
                    int row = mf * 16 + hi16 * 4 + r;
                    int col = nf * 16 + lrow;
                    float v = fmaxf(acc[mf][nf][r] + bv[nf], 0.f);
                    *(float*)((char*)tb + ((((row << 6) + col) << 2) ^ ((row & 3) << 5))) = v;
                }
#pragma unroll
        for (int mf = 0; mf < 2; ++mf)
#pragma unroll
            for (int kt = 0; kt < 2; ++kt) {
                int row = mf * 16 + lrow;
                float v[8];
                __builtin_memcpy(v, (char*)tb + ((((row << 6) + kt * 32 + koff) << 2) ^ ((row & 3) << 5)), 32);
                split8(v, aH[mf][kt], aL[mf][kt]);
            }
    }

    f32x4 acc3[2];
    acc3[0] = (f32x4){0.f, 0.f, 0.f, 0.f};
    acc3[1] = (f32x4){0.f, 0.f, 0.f, 0.f};
#pragma unroll
    for (int kt = 0; kt < 2; ++kt) {
        short8v bH = *((const short8v*)w3h + kt * 64 + lane);
        short8v bL = *((const short8v*)w3l + kt * 64 + lane);
#pragma unroll
        for (int mf = 0; mf < 2; ++mf) {
            acc3[mf] = __builtin_amdgcn_mfma_f32_16x16x32_bf16(aH[mf][kt], bH, acc3[mf], 0, 0, 0);
            acc3[mf] = __builtin_amdgcn_mfma_f32_16x16x32_bf16(aH[mf][kt], bL, acc3[mf], 0, 0, 0);
            acc3[mf] = __builtin_amdgcn_mfma_f32_16x16x32_bf16(aL[mf][kt], bH, acc3[mf], 0, 0, 0);
        }
    }
#pragma unroll
    for (int mf = 0; mf < 2; ++mf)
#pragma unroll
        for (int r = 0; r < 4; ++r) {
            float z  = acc3[mf][r] + b3v;
            float zm = (lrow < NCLS) ? z : -1e30f;
            float m  = zm;
#pragma unroll
            for (int mask = 1; mask < 16; mask <<= 1)
                m = fmaxf(m, __shfl_xor(m, mask));
            float ev = (lrow < NCLS) ? expf(z - m) : 0.f;
            float ss = ev;
#pragma unroll
            for (int mask = 1; mask < 16; mask <<= 1)
                ss += __shfl_xor(ss, mask);
            float res = z - (m + logf(ss));
            int row = m0 + mf * 16 + hi16 * 4 + r;
            if (row < M && lrow < NCLS)
                out[(size_t)row * NCLS + lrow] = res;
        }
}

extern "C" void kernel_launch(void* const* d_in, const int* in_sizes, int n_in,
                              void* d_out, int out_size, void* d_ws, size_t ws_size,
                              hipStream_t stream) {
    const float* x   = (const float*)d_in[0];
    const int*   ei  = (const int*)d_in[1];
    const float* W1  = (const float*)d_in[2];
    const float* b1  = (const float*)d_in[3];
    const float* W2  = (const float*)d_in[4];
    const float* b2  = (const float*)d_in[5];
    const float* Wf1 = (const float*)d_in[6];
    const float* bf1 = (const float*)d_in[7];
    const float* Wf2 = (const float*)d_in[8];
    const float* bf2 = (const float*)d_in[9];
    const float* Wf3 = (const float*)d_in[10];
    const float* bf3 = (const float*)d_in[11];

    const int N = N_NODES;
    const int E = in_sizes[1] / 2;
    float* outp = (float*)d_out;

    char* p = (char*)d_ws;
    auto alloc = [&](size_t bytes) {
        char* q = p;
        p += (bytes + 255) & ~(size_t)255;
        return q;
    };
    int*            counts   = (int*)           alloc((size_t)N * 4);
    int*            offsets  = (int*)           alloc((size_t)(N + 1) * 4);
    int*            cursor   = (int*)           alloc((size_t)N * 4);
    int*            local_ex = (int*)           alloc((size_t)N * 4);
    int*            blocksum = (int*)           alloc((size_t)NBLK * 4);
    int*            blockoff = (int*)           alloc((size_t)NBLK * 4);
    float*          dinv     = (float*)         alloc((size_t)N * 4);
    int2*           pay      = (int2*)          alloc((size_t)E * 8);
    unsigned short* w1fh     = (unsigned short*)alloc((size_t)NKT1 * 4 * 64 * 8 * 2);
    unsigned short* w1fl     = (unsigned short*)alloc((size_t)NKT1 * 4 * 64 * 8 * 2);
    unsigned short* w2fh     = (unsigned short*)alloc((size_t)2 * 4 * 64 * 8 * 2);
    unsigned short* w2fl     = (unsigned short*)alloc((size_t)2 * 4 * 64 * 8 * 2);
    unsigned short* wf1h     = (unsigned short*)alloc((size_t)2 * 4 * 64 * 8 * 2);
    unsigned short* wf1l     = (unsigned short*)alloc((size_t)2 * 4 * 64 * 8 * 2);
    unsigned short* wf2h     = (unsigned short*)alloc((size_t)2 * 4 * 64 * 8 * 2);
    unsigned short* wf2l     = (unsigned short*)alloc((size_t)2 * 4 * 64 * 8 * 2);
    unsigned short* wf3h     = (unsigned short*)alloc((size_t)2 * 1 * 64 * 8 * 2);
    unsigned short* wf3l     = (unsigned short*)alloc((size_t)2 * 1 * 64 * 8 * 2);
    unsigned short* bufH16   = (unsigned short*)alloc((size_t)N * HID * 2);
    float*          bufF     = (float*)         alloc((size_t)N * HID * 4);

    const int* src = ei;
    const int* dst = ei + E;

    hipMemsetAsync(counts, 0, (size_t)N * 4, stream);
    int ge = (E + 255) / 256;
    hist_kernel<<<ge, 256, 0, stream>>>(dst, counts, E);
    dinv_kernel<<<(N + 255) / 256, 256, 0, stream>>>(counts, dinv, N);
    scan_p1<<<NBLK, SCAN_BLK, 0, stream>>>(counts, local_ex, blocksum, N);
    scan_p2<<<1, 128, 0, stream>>>(blocksum, blockoff, &offsets[N], NBLK);
    scan_p3<<<NBLK, SCAN_BLK, 0, stream>>>(local_ex, blockoff, offsets, cursor, N);
    scatter_kernel<<<ge, 256, 0, stream>>>(src, dst, dinv, cursor, pay, E);

    convert_wfrag_g<<<(NKT1 * 4 * 64 + 255) / 256, 256, 0, stream>>>(W1, N_FEAT, 64, NKT1, 4, w1fh, w1fl);
    convert_wfrag_g<<<2, 256, 0, stream>>>(W2, 64, 64, 2, 4, w2fh, w2fl);
    convert_wfrag_g<<<2, 256, 0, stream>>>(Wf1, 64, 64, 2, 4, wf1h, wf1l);
    convert_wfrag_g<<<2, 256, 0, stream>>>(Wf2, 64, 64, 2, 4, wf2h, wf2l);
    convert_wfrag_g<<<1, 256, 0, stream>>>(Wf3, 64, NCLS, 2, 1, wf3h, wf3l);

    // layer 1
    gemm_xw_v9<<<(N + 127) / 128, 256, 0, stream>>>(x, w1fh, bufH16, N);
    aggregate_v4<<<(N + 3) / 4, 256, 0, stream>>>(bufH16, pay, offsets, dinv, b1, bufF, N);
    // layer 2
    gemm_hid_v3<<<(N + 127) / 128, 256, 0, stream>>>(bufF, w2fh, w2fl, bufH16, N);
    aggregate_v4<<<(N + 3) / 4, 256, 0, stream>>>(bufH16, pay, offsets, dinv, b2, bufF, N);
    // head
    mlp_mfma<<<(N + 127) / 128, 256, 0, stream>>>(bufF, wf1h, wf1l, wf2h, wf2l, wf3h, wf3l,
                                                  bf1, bf2, bf3, outp, N);
}

// Round 11
// 632.556 us; speedup vs baseline: 1.1544x; 1.1544x over previous
//
#include <hip/hip_runtime.h>
#include <hip/hip_bf16.h>

#define N_NODES 100000
#define N_FEAT  1433
#define NKT1    46       // k-tiles of 32 for K=1433->1472
#define HID     64
#define NCLS    7
#define SCAN_BLK 1024
#define NBLK    ((N_NODES + SCAN_BLK - 1) / SCAN_BLK)   // 98

typedef __attribute__((ext_vector_type(8))) short short8v;
typedef __attribute__((ext_vector_type(4))) float f32x4;

__device__ __forceinline__ unsigned short f2bf(float v) {
    unsigned u = __float_as_uint(v);
    unsigned r = (u + 0x7FFFu + ((u >> 16) & 1u)) >> 16;   // RNE
    return (unsigned short)r;
}
__device__ __forceinline__ float bf2f(unsigned short h) {
    return __uint_as_float(((unsigned)h) << 16);
}

// packed f32x2 -> bf16x2 via v_cvt_pk_bf16_f32 (RNE), compiler-scheduled
__device__ __forceinline__ unsigned pk2(float a, float b) {
    union { __hip_bfloat162 h2; unsigned u; } cv;
    cv.h2 = __float22bfloat162_rn(make_float2(a, b));
    return cv.u;
}
__device__ __forceinline__ short8v cvt8(const float* v) {
    union { unsigned u[4]; short8v s; } r;
#pragma unroll
    for (int i = 0; i < 4; ++i) r.u[i] = pk2(v[2 * i], v[2 * i + 1]);
    return r.s;
}

// ---------------- W -> fragment-major bf16 hi/lo (device body) ----------------
__device__ __forceinline__
void convert_body(const float* __restrict__ W, int K, int ncols, int nfc, int tid, int total,
                  unsigned short* __restrict__ wfh, unsigned short* __restrict__ wfl) {
    if (tid >= total) return;
    int rem  = tid % (nfc * 64);
    int kt   = tid / (nfc * 64);
    int nf   = rem >> 6;
    int lane = rem & 63;
    int n  = nf * 16 + (lane & 15);
    int kb = kt * 32 + ((lane >> 4) << 3);
    short8v hi, lo;
#pragma unroll
    for (int j = 0; j < 8; ++j) {
        int k = kb + j;
        float v = (k < K && n < ncols) ? W[(size_t)k * ncols + n] : 0.f;
        unsigned short h = f2bf(v);
        hi[j] = (short)h;
        lo[j] = (short)f2bf(v - bf2f(h));
    }
    *(short8v*)(wfh + (size_t)tid * 8) = hi;
    *(short8v*)(wfl + (size_t)tid * 8) = lo;
}

// ---------------- prep1: [converts | hist] block-role-split ----------------
// blocks 0..45: W1 table; 46-47: W2; 48-49: Wf1; 50-51: Wf2; 52: Wf3; 53+: hist
#define CVT_BLKS 53
__global__ __launch_bounds__(256)
void prep1(const float* __restrict__ W1,  unsigned short* w1fh, unsigned short* w1fl,
           const float* __restrict__ W2,  unsigned short* w2fh, unsigned short* w2fl,
           const float* __restrict__ Wf1, unsigned short* wf1h, unsigned short* wf1l,
           const float* __restrict__ Wf2, unsigned short* wf2h, unsigned short* wf2l,
           const float* __restrict__ Wf3, unsigned short* wf3h, unsigned short* wf3l,
           const int* __restrict__ dst, int* __restrict__ counts, int E) {
    int b = blockIdx.x;
    int t = threadIdx.x;
    if (b >= CVT_BLKS) {
        int e = (b - CVT_BLKS) * 256 + t;
        if (e < E) atomicAdd(&counts[dst[e]], 1);
        return;
    }
    if (b < 46)       convert_body(W1,  N_FEAT, 64, 4, b * 256 + t,        NKT1 * 4 * 64, w1fh, w1fl);
    else if (b < 48)  convert_body(W2,  64, 64,   4, (b - 46) * 256 + t,   2 * 4 * 64,    w2fh, w2fl);
    else if (b < 50)  convert_body(Wf1, 64, 64,   4, (b - 48) * 256 + t,   2 * 4 * 64,    wf1h, wf1l);
    else if (b < 52)  convert_body(Wf2, 64, 64,   4, (b - 50) * 256 + t,   2 * 4 * 64,    wf2h, wf2l);
    else              convert_body(Wf3, 64, NCLS, 1, (b - 52) * 256 + t,   2 * 1 * 64,    wf3h, wf3l);
}

// ---------------- 3-phase parallel exclusive scan (p1 fuses dinv) ----------------
__global__ __launch_bounds__(SCAN_BLK)
void scan_p1d(const int* __restrict__ counts, int* __restrict__ local_ex,
              int* __restrict__ blocksum, float* __restrict__ dinv, int n) {
    __shared__ int sh[SCAN_BLK];
    int t = threadIdx.x;
    int i = blockIdx.x * SCAN_BLK + t;
    int v = (i < n) ? counts[i] : 0;
    if (i < n) dinv[i] = rsqrtf((float)(v + 1));   // +1 = self loop
    sh[t] = v;
    __syncthreads();
    for (int off = 1; off < SCAN_BLK; off <<= 1) {
        int u = (t >= off) ? sh[t - off] : 0;
        __syncthreads();
        sh[t] += u;
        __syncthreads();
    }
    if (i < n) local_ex[i] = sh[t] - v;      // exclusive
    if (t == SCAN_BLK - 1) blocksum[blockIdx.x] = sh[t];
}

__global__ __launch_bounds__(128)
void scan_p2(int* __restrict__ blocksum, int* __restrict__ blockoff,
             int* __restrict__ offsets_last, int nb) {
    __shared__ int sh[128];
    int t = threadIdx.x;
    int v = (t < nb) ? blocksum[t] : 0;
    sh[t] = v;
    __syncthreads();
    for (int off = 1; off < 128; off <<= 1) {
        int u = (t >= off) ? sh[t - off] : 0;
        __syncthreads();
        sh[t] += u;
        __syncthreads();
    }
    if (t < nb) blockoff[t] = sh[t] - v;
    if (t == nb - 1) *offsets_last = sh[t];
}

__global__ __launch_bounds__(SCAN_BLK)
void scan_p3(const int* __restrict__ local_ex, const int* __restrict__ blockoff,
             int* __restrict__ offsets, int* __restrict__ cursor, int n) {
    int i = blockIdx.x * SCAN_BLK + threadIdx.x;
    if (i < n) {
        int v = local_ex[i] + blockoff[blockIdx.x];
        offsets[i] = v;
        cursor[i]  = v;
    }
}

// masked tail fragment load (executes once per kernel)
__device__ __forceinline__ short8v load_frag_f32(const float* __restrict__ row, int kk) {
    float v[8];
#pragma unroll
    for (int j = 0; j < 8; ++j) v[j] = (kk + j < N_FEAT) ? row[kk + j] : 0.f;
    return cvt8(v);
}

// ---------------- GEMM1 body (r9 v8: W1 hi-only, cvt_pk, 32 rows/wave) ----------------
__device__ __forceinline__
void gemm_xw_body(int blk, const float* __restrict__ X,
                  const unsigned short* __restrict__ wfh,
                  unsigned short* __restrict__ H16, int M) {
    const int t    = threadIdx.x;
    const int lane = t & 63;
    const int w    = t >> 6;
    const int m0   = blk * 128 + w * 32;
    const int lrow = lane & 15;
    const int koff = (lane >> 4) * 8;

    f32x4 acc[2][4];
#pragma unroll
    for (int i = 0; i < 2; ++i)
#pragma unroll
        for (int j = 0; j < 4; ++j) acc[i][j] = (f32x4){0.f, 0.f, 0.f, 0.f};

    const float* a0 = X + (size_t)min(m0 + lrow,      M - 1) * N_FEAT;
    const float* a1 = X + (size_t)min(m0 + 16 + lrow, M - 1) * N_FEAT;
    const short8v* bh = (const short8v*)wfh + lane;   // + (kt*4+nf)*64

#pragma unroll 4
    for (int kt = 0; kt < 44; ++kt) {
        int kk = kt * 32 + koff;
        short8v aH[2], bH[4];
        float v0[8], v1[8];
        __builtin_memcpy(v0, a0 + kk, 32);
        __builtin_memcpy(v1, a1 + kk, 32);
        aH[0] = cvt8(v0);
        aH[1] = cvt8(v1);
#pragma unroll
        for (int nf = 0; nf < 4; ++nf)
            bH[nf] = bh[(kt * 4 + nf) * 64];
#pragma unroll
        for (int mf = 0; mf < 2; ++mf)
#pragma unroll
            for (int nf = 0; nf < 4; ++nf)
                acc[mf][nf] = __builtin_amdgcn_mfma_f32_16x16x32_bf16(aH[mf], bH[nf], acc[mf][nf], 0, 0, 0);
    }
    {   // tail kt=44 (k 1408..1439, masked >= 1433)
        const int kt = 44;
        int kk = kt * 32 + koff;
        short8v aH[2], bH[4];
        aH[0] = load_frag_f32(a0, kk);
        aH[1] = load_frag_f32(a1, kk);
#pragma unroll
        for (int nf = 0; nf < 4; ++nf)
            bH[nf] = bh[(kt * 4 + nf) * 64];
#pragma unroll
        for (int mf = 0; mf < 2; ++mf)
#pragma unroll
            for (int nf = 0; nf < 4; ++nf)
                acc[mf][nf] = __builtin_amdgcn_mfma_f32_16x16x32_bf16(aH[mf], bH[nf], acc[mf][nf], 0, 0, 0);
    }
    // C: col = lane&15, row = (lane>>4)*4 + reg
#pragma unroll
    for (int mf = 0; mf < 2; ++mf)
#pragma unroll
        for (int r = 0; r < 4; ++r) {
            int row = m0 + mf * 16 + ((lane >> 4) << 2) + r;
            if (row < M) {
#pragma unroll
                for (int nf = 0; nf < 4; ++nf)
                    H16[(size_t)row * 64 + nf * 16 + lrow] = f2bf(acc[mf][nf][r]);
            }
        }
}

// ---------------- scatter body: single int2 payload (src, weight) ----------------
__device__ __forceinline__
void scatter_body(int blk, const int* __restrict__ src, const int* __restrict__ dst,
                  const float* __restrict__ dinv, int* __restrict__ cursor,
                  int2* __restrict__ pay, int E) {
    int e = blk * 256 + threadIdx.x;
    if (e >= E) return;
    int s = src[e], d = dst[e];
    int pos = atomicAdd(&cursor[d], 1);
    pay[pos] = make_int2(s, __float_as_int(dinv[s] * dinv[d]));
}

// ---------------- mega2: [gemm | scatter] block-role-split ----------------
__global__ __launch_bounds__(256)
void mega2(const float* __restrict__ X, const unsigned short* __restrict__ w1fh,
           unsigned short* __restrict__ H16, int M, int GB,
           const int* __restrict__ src, const int* __restrict__ dst,
           const float* __restrict__ dinv, int* __restrict__ cursor,
           int2* __restrict__ pay, int E) {
    int b = blockIdx.x;
    if (b < GB) gemm_xw_body(b, X, w1fh, H16, M);
    else        scatter_body(b - GB, src, dst, dinv, cursor, pay, E);
}

// ---------------- GEMM2 v3: [M,64] f32 @ [64,64], cvt_pk, frag-major W2 hi/lo ----------------
__global__ __launch_bounds__(256)
void gemm_hid_v3(const float* __restrict__ A,
                 const unsigned short* __restrict__ wfh,
                 const unsigned short* __restrict__ wfl,
                 unsigned short* __restrict__ H16, int M) {
    const int t    = threadIdx.x;
    const int lane = t & 63;
    const int w    = t >> 6;
    const int m0   = blockIdx.x * 128 + w * 32;
    const int lrow = lane & 15;
    const int koff = (lane >> 4) * 8;

    f32x4 acc[2][4];
#pragma unroll
    for (int i = 0; i < 2; ++i)
#pragma unroll
        for (int j = 0; j < 4; ++j) acc[i][j] = (f32x4){0.f, 0.f, 0.f, 0.f};

    const float* a0 = A + (size_t)min(m0 + lrow,      M - 1) * 64;
    const float* a1 = A + (size_t)min(m0 + 16 + lrow, M - 1) * 64;
    const short8v* bh = (const short8v*)wfh + lane;
    const short8v* bl = (const short8v*)wfl + lane;

#pragma unroll
    for (int kt = 0; kt < 2; ++kt) {
        int kk = kt * 32 + koff;
        short8v aH[2], bH[4], bL[4];
        float v0[8], v1[8];
        __builtin_memcpy(v0, a0 + kk, 32);
        __builtin_memcpy(v1, a1 + kk, 32);
        aH[0] = cvt8(v0);
        aH[1] = cvt8(v1);
#pragma unroll
        for (int nf = 0; nf < 4; ++nf) {
            bH[nf] = bh[(kt * 4 + nf) * 64];
            bL[nf] = bl[(kt * 4 + nf) * 64];
        }
#pragma unroll
        for (int mf = 0; mf < 2; ++mf)
#pragma unroll
            for (int nf = 0; nf < 4; ++nf) {
                acc[mf][nf] = __builtin_amdgcn_mfma_f32_16x16x32_bf16(aH[mf], bH[nf], acc[mf][nf], 0, 0, 0);
                acc[mf][nf] = __builtin_amdgcn_mfma_f32_16x16x32_bf16(aH[mf], bL[nf], acc[mf][nf], 0, 0, 0);
            }
    }
#pragma unroll
    for (int mf = 0; mf < 2; ++mf)
#pragma unroll
        for (int r = 0; r < 4; ++r) {
            int row = m0 + mf * 16 + ((lane >> 4) << 2) + r;
            if (row < M) {
#pragma unroll
                for (int nf = 0; nf < 4; ++nf)
                    H16[(size_t)row * 64 + nf * 16 + lrow] = f2bf(acc[mf][nf][r]);
            }
        }
}

// ---------------- aggregate v4: 8 edges/iter, 2 gathers in flight ----------------
__global__ __launch_bounds__(256)
void aggregate_v4(const unsigned short* __restrict__ h16, const int2* __restrict__ pay,
                  const int* __restrict__ offsets,
                  const float* __restrict__ dinv, const float* __restrict__ bias,
                  float* __restrict__ out, int n) {
    int wid  = (blockIdx.x * blockDim.x + threadIdx.x) >> 6;
    int lane = threadIdx.x & 63;
    if (wid >= n) return;
    const int g  = lane >> 4;          // edge subgroup 0..3
    const int f4 = (lane & 15) * 4;    // feature base

    float a0 = 0.f, a1 = 0.f, a2 = 0.f, a3 = 0.f;
    int beg = offsets[wid], end = offsets[wid + 1];
    int cnt = end - beg;
    int nq  = cnt >> 3;
    int e   = beg + g;
#pragma unroll 2
    for (int q = 0; q < nq; ++q, e += 8) {
        int2 p1 = pay[e];
        int2 p2 = pay[e + 4];
        float w1 = __int_as_float(p1.y);
        float w2 = __int_as_float(p2.y);
        ushort4 h1 = *(const ushort4*)(h16 + (size_t)p1.x * HID + f4);
        ushort4 h2 = *(const ushort4*)(h16 + (size_t)p2.x * HID + f4);
        a0 = fmaf(bf2f(h1.x), w1, a0); a1 = fmaf(bf2f(h1.y), w1, a1);
        a2 = fmaf(bf2f(h1.z), w1, a2); a3 = fmaf(bf2f(h1.w), w1, a3);
        a0 = fmaf(bf2f(h2.x), w2, a0); a1 = fmaf(bf2f(h2.y), w2, a1);
        a2 = fmaf(bf2f(h2.z), w2, a2); a3 = fmaf(bf2f(h2.w), w2, a3);
    }
    int rem  = cnt & 7;
    int base = beg + nq * 8;
    if (g < rem) {
        int2  pw  = pay[base + g];
        float wgt = __int_as_float(pw.y);
        ushort4 hv = *(const ushort4*)(h16 + (size_t)pw.x * HID + f4);
        a0 = fmaf(bf2f(hv.x), wgt, a0); a1 = fmaf(bf2f(hv.y), wgt, a1);
        a2 = fmaf(bf2f(hv.z), wgt, a2); a3 = fmaf(bf2f(hv.w), wgt, a3);
    }
    if (g + 4 < rem) {
        int2  pw  = pay[base + g + 4];
        float wgt = __int_as_float(pw.y);
        ushort4 hv = *(const ushort4*)(h16 + (size_t)pw.x * HID + f4);
        a0 = fmaf(bf2f(hv.x), wgt, a0); a1 = fmaf(bf2f(hv.y), wgt, a1);
        a2 = fmaf(bf2f(hv.z), wgt, a2); a3 = fmaf(bf2f(hv.w), wgt, a3);
    }
    if (g == 0) {   // self loop
        float di = dinv[wid];
        float w2 = di * di;
        ushort4 hv = *(const ushort4*)(h16 + (size_t)wid * HID + f4);
        a0 = fmaf(bf2f(hv.x), w2, a0); a1 = fmaf(bf2f(hv.y), w2, a1);
        a2 = fmaf(bf2f(hv.z), w2, a2); a3 = fmaf(bf2f(hv.w), w2, a3);
    }
    a0 += __shfl_xor(a0, 16); a0 += __shfl_xor(a0, 32);
    a1 += __shfl_xor(a1, 16); a1 += __shfl_xor(a1, 32);
    a2 += __shfl_xor(a2, 16); a2 += __shfl_xor(a2, 32);
    a3 += __shfl_xor(a3, 16); a3 += __shfl_xor(a3, 32);
    if (g == 0) {
        float4 bv = *(const float4*)&bias[f4];
        float4 o;
        o.x = fmaxf(a0 + bv.x, 0.f);
        o.y = fmaxf(a1 + bv.y, 0.f);
        o.z = fmaxf(a2 + bv.z, 0.f);
        o.w = fmaxf(a3 + bv.w, 0.f);
        *(float4*)&out[(size_t)wid * HID + f4] = o;
    }
}

// ---------------- fused MLP head via MFMA + butterfly log_softmax ----------------
__device__ __forceinline__ void split8(const float* v, short8v& h, short8v& l) {
    h = cvt8(v);
    float res[8];
#pragma unroll
    for (int j = 0; j < 8; ++j) res[j] = v[j] - bf2f((unsigned short)h[j]);
    l = cvt8(res);
}

__global__ __launch_bounds__(256)
void mlp_mfma(const float* __restrict__ y,
              const unsigned short* __restrict__ w1h, const unsigned short* __restrict__ w1l,
              const unsigned short* __restrict__ w2h, const unsigned short* __restrict__ w2l,
              const unsigned short* __restrict__ w3h, const unsigned short* __restrict__ w3l,
              const float* __restrict__ bf1, const float* __restrict__ bf2,
              const float* __restrict__ bf3,
              float* __restrict__ out, int M) {
    __shared__ float tbuf[4][32 * 64];
    const int t    = threadIdx.x;
    const int lane = t & 63;
    const int w    = t >> 6;
    const int m0   = blockIdx.x * 128 + w * 32;
    const int lrow = lane & 15;
    const int hi16 = lane >> 4;
    const int koff = hi16 * 8;
    float* tb = tbuf[w];

    float b1v[4], b2v[4];
#pragma unroll
    for (int nf = 0; nf < 4; ++nf) {
        b1v[nf] = bf1[nf * 16 + lrow];
        b2v[nf] = bf2[nf * 16 + lrow];
    }
    float b3v = (lrow < NCLS) ? bf3[lrow] : 0.f;

    short8v aH[2][2], aL[2][2];   // [mf][kt]
    {
        const float* a0 = y + (size_t)min(m0 + lrow,      M - 1) * 64;
        const float* a1 = y + (size_t)min(m0 + 16 + lrow, M - 1) * 64;
#pragma unroll
        for (int kt = 0; kt < 2; ++kt) {
            float v0[8], v1[8];
            __builtin_memcpy(v0, a0 + kt * 32 + koff, 32);
            __builtin_memcpy(v1, a1 + kt * 32 + koff, 32);
            split8(v0, aH[0][kt], aL[0][kt]);
            split8(v1, aH[1][kt], aL[1][kt]);
        }
    }

#pragma unroll
    for (int layer = 0; layer < 2; ++layer) {
        const unsigned short* wh = layer ? w2h : w1h;
        const unsigned short* wl = layer ? w2l : w1l;
        const float* bv = layer ? b2v : b1v;
        f32x4 acc[2][4];
#pragma unroll
        for (int i = 0; i < 2; ++i)
#pragma unroll
            for (int j = 0; j < 4; ++j) acc[i][j] = (f32x4){0.f, 0.f, 0.f, 0.f};
#pragma unroll
        for (int kt = 0; kt < 2; ++kt) {
            short8v bH[4], bL[4];
#pragma unroll
            for (int nf = 0; nf < 4; ++nf) {
                bH[nf] = *((const short8v*)wh + (kt * 4 + nf) * 64 + lane);
                bL[nf] = *((const short8v*)wl + (kt * 4 + nf) * 64 + lane);
            }
#pragma unroll
            for (int mf = 0; mf < 2; ++mf)
#pragma unroll
                for (int nf = 0; nf < 4; ++nf) {
                    acc[mf][nf] = __builtin_amdgcn_mfma_f32_16x16x32_bf16(aH[mf][kt], bH[nf], acc[mf][nf], 0, 0, 0);
                    acc[mf][nf] = __builtin_amdgcn_mfma_f32_16x16x32_bf16(aH[mf][kt], bL[nf], acc[mf][nf], 0, 0, 0);
                    acc[mf][nf] = __builtin_amdgcn_mfma_f32_16x16x32_bf16(aL[mf][kt], bH[nf], acc[mf][nf], 0, 0, 0);
                }
        }
#pragma unroll
        for (int mf = 0; mf < 2; ++mf)
#pragma unroll
            for (int nf = 0; nf < 4; ++nf)
#pragma unroll
                for (int r = 0; r < 4; ++r) {
                    int row = mf * 16 + hi16 * 4 + r;
                    int col = nf * 16 + lrow;
                    float v = fmaxf(acc[mf][nf][r] + bv[nf], 0.f);
                    *(float*)((char*)tb + ((((row << 6) + col) << 2) ^ ((row & 3) << 5))) = v;
                }
#pragma unroll
        for (int mf = 0; mf < 2; ++mf)
#pragma unroll
            for (int kt = 0; kt < 2; ++kt) {
                int row = mf * 16 + lrow;
                float v[8];
                __builtin_memcpy(v, (char*)tb + ((((row << 6) + kt * 32 + koff) << 2) ^ ((row & 3) << 5)), 32);
                split8(v, aH[mf][kt], aL[mf][kt]);
            }
    }

    f32x4 acc3[2];
    acc3[0] = (f32x4){0.f, 0.f, 0.f, 0.f};
    acc3[1] = (f32x4){0.f, 0.f, 0.f, 0.f};
#pragma unroll
    for (int kt = 0; kt < 2; ++kt) {
        short8v bH = *((const short8v*)w3h + kt * 64 + lane);
        short8v bL = *((const short8v*)w3l + kt * 64 + lane);
#pragma unroll
        for (int mf = 0; mf < 2; ++mf) {
            acc3[mf] = __builtin_amdgcn_mfma_f32_16x16x32_bf16(aH[mf][kt], bH, acc3[mf], 0, 0, 0);
            acc3[mf] = __builtin_amdgcn_mfma_f32_16x16x32_bf16(aH[mf][kt], bL, acc3[mf], 0, 0, 0);
            acc3[mf] = __builtin_amdgcn_mfma_f32_16x16x32_bf16(aL[mf][kt], bH, acc3[mf], 0, 0, 0);
        }
    }
#pragma unroll
    for (int mf = 0; mf < 2; ++mf)
#pragma unroll
        for (int r = 0; r < 4; ++r) {
            float z  = acc3[mf][r] + b3v;
            float zm = (lrow < NCLS) ? z : -1e30f;
            float m  = zm;
#pragma unroll
            for (int mask = 1; mask < 16; mask <<= 1)
                m = fmaxf(m, __shfl_xor(m, mask));
            float ev = (lrow < NCLS) ? expf(z - m) : 0.f;
            float ss = ev;
#pragma unroll
            for (int mask = 1; mask < 16; mask <<= 1)
                ss += __shfl_xor(ss, mask);
            float res = z - (m + logf(ss));
            int row = m0 + mf * 16 + hi16 * 4 + r;
            if (row < M && lrow < NCLS)
                out[(size_t)row * NCLS + lrow] = res;
        }
}

extern "C" void kernel_launch(void* const* d_in, const int* in_sizes, int n_in,
                              void* d_out, int out_size, void* d_ws, size_t ws_size,
                              hipStream_t stream) {
    const float* x   = (const float*)d_in[0];
    const int*   ei  = (const int*)d_in[1];
    const float* W1  = (const float*)d_in[2];
    const float* b1  = (const float*)d_in[3];
    const float* W2  = (const float*)d_in[4];
    const float* b2  = (const float*)d_in[5];
    const float* Wf1 = (const float*)d_in[6];
    const float* bf1 = (const float*)d_in[7];
    const float* Wf2 = (const float*)d_in[8];
    const float* bf2 = (const float*)d_in[9];
    const float* Wf3 = (const float*)d_in[10];
    const float* bf3 = (const float*)d_in[11];

    const int N = N_NODES;
    const int E = in_sizes[1] / 2;
    float* outp = (float*)d_out;

    char* p = (char*)d_ws;
    auto alloc = [&](size_t bytes) {
        char* q = p;
        p += (bytes + 255) & ~(size_t)255;
        return q;
    };
    int*            counts   = (int*)           alloc((size_t)N * 4);
    int*            offsets  = (int*)           alloc((size_t)(N + 1) * 4);
    int*            cursor   = (int*)           alloc((size_t)N * 4);
    int*            local_ex = (int*)           alloc((size_t)N * 4);
    int*            blocksum = (int*)           alloc((size_t)NBLK * 4);
    int*            blockoff = (int*)           alloc((size_t)NBLK * 4);
    float*          dinv     = (float*)         alloc((size_t)N * 4);
    int2*           pay      = (int2*)          alloc((size_t)E * 8);
    unsigned short* w1fh     = (unsigned short*)alloc((size_t)NKT1 * 4 * 64 * 8 * 2);
    unsigned short* w1fl     = (unsigned short*)alloc((size_t)NKT1 * 4 * 64 * 8 * 2);
    unsigned short* w2fh     = (unsigned short*)alloc((size_t)2 * 4 * 64 * 8 * 2);
    unsigned short* w2fl     = (unsigned short*)alloc((size_t)2 * 4 * 64 * 8 * 2);
    unsigned short* wf1h     = (unsigned short*)alloc((size_t)2 * 4 * 64 * 8 * 2);
    unsigned short* wf1l     = (unsigned short*)alloc((size_t)2 * 4 * 64 * 8 * 2);
    unsigned short* wf2h     = (unsigned short*)alloc((size_t)2 * 4 * 64 * 8 * 2);
    unsigned short* wf2l     = (unsigned short*)alloc((size_t)2 * 4 * 64 * 8 * 2);
    unsigned short* wf3h     = (unsigned short*)alloc((size_t)2 * 1 * 64 * 8 * 2);
    unsigned short* wf3l     = (unsigned short*)alloc((size_t)2 * 1 * 64 * 8 * 2);
    unsigned short* bufH16   = (unsigned short*)alloc((size_t)N * HID * 2);
    float*          bufF     = (float*)         alloc((size_t)N * HID * 4);

    const int* src = ei;
    const int* dst = ei + E;

    hipMemsetAsync(counts, 0, (size_t)N * 4, stream);
    int ge = (E + 255) / 256;     // 12500 hist/scatter blocks
    int GB = (N + 127) / 128;     // 782 gemm blocks

    // [converts | hist]
    prep1<<<CVT_BLKS + ge, 256, 0, stream>>>(W1, w1fh, w1fl, W2, w2fh, w2fl,
                                             Wf1, wf1h, wf1l, Wf2, wf2h, wf2l,
                                             Wf3, wf3h, wf3l, dst, counts, E);
    scan_p1d<<<NBLK, SCAN_BLK, 0, stream>>>(counts, local_ex, blocksum, dinv, N);
    scan_p2<<<1, 128, 0, stream>>>(blocksum, blockoff, &offsets[N], NBLK);
    scan_p3<<<NBLK, SCAN_BLK, 0, stream>>>(local_ex, blockoff, offsets, cursor, N);

    // [gemm layer1 | scatter]
    mega2<<<GB + ge, 256, 0, stream>>>(x, w1fh, bufH16, N, GB,
                                       src, dst, dinv, cursor, pay, E);

    aggregate_v4<<<(N + 3) / 4, 256, 0, stream>>>(bufH16, pay, offsets, dinv, b1, bufF, N);
    gemm_hid_v3<<<(N + 127) / 128, 256, 0, stream>>>(bufF, w2fh, w2fl, bufH16, N);
    aggregate_v4<<<(N + 3) / 4, 256, 0, stream>>>(bufH16, pay, offsets, dinv, b2, bufF, N);
    mlp_mfma<<<(N + 127) / 128, 256, 0, stream>>>(bufF, wf1h, wf1l, wf2h, wf2l, wf3h, wf3l,
                                                  bf1, bf2, bf3, outp, N);
}

// Round 12
// 602.457 us; speedup vs baseline: 1.2121x; 1.0500x over previous
//
#include <hip/hip_runtime.h>
#include <hip/hip_bf16.h>

#define N_NODES 100000
#define N_FEAT  1433
#define NKT1    46       // k-tiles of 32 for K=1433->1472
#define HID     64
#define NCLS    7
#define SCAN_BLK 1024
#define NBLK    ((N_NODES + SCAN_BLK - 1) / SCAN_BLK)   // 98

typedef __attribute__((ext_vector_type(8))) short short8v;
typedef __attribute__((ext_vector_type(4))) float f32x4;

__device__ __forceinline__ unsigned short f2bf(float v) {
    unsigned u = __float_as_uint(v);
    unsigned r = (u + 0x7FFFu + ((u >> 16) & 1u)) >> 16;   // RNE
    return (unsigned short)r;
}
__device__ __forceinline__ float bf2f(unsigned short h) {
    return __uint_as_float(((unsigned)h) << 16);
}

// packed f32x2 -> bf16x2 via v_cvt_pk_bf16_f32 (RNE), compiler-scheduled
__device__ __forceinline__ unsigned pk2(float a, float b) {
    union { __hip_bfloat162 h2; unsigned u; } cv;
    cv.h2 = __float22bfloat162_rn(make_float2(a, b));
    return cv.u;
}
__device__ __forceinline__ short8v cvt8(const float* v) {
    union { unsigned u[4]; short8v s; } r;
#pragma unroll
    for (int i = 0; i < 4; ++i) r.u[i] = pk2(v[2 * i], v[2 * i + 1]);
    return r.s;
}

// async global->LDS, 4 bytes/lane, LDS dest = uniform base + lane*4
__device__ __forceinline__ void gl_lds4(const float* g, char* l) {
    __builtin_amdgcn_global_load_lds(
        (const __attribute__((address_space(1))) unsigned*)g,
        (__attribute__((address_space(3))) unsigned*)l, 4, 0, 0);
}

// ---------------- W -> fragment-major bf16 hi/lo (device body) ----------------
__device__ __forceinline__
void convert_body(const float* __restrict__ W, int K, int ncols, int nfc, int tid, int total,
                  unsigned short* __restrict__ wfh, unsigned short* __restrict__ wfl) {
    if (tid >= total) return;
    int rem  = tid % (nfc * 64);
    int kt   = tid / (nfc * 64);
    int nf   = rem >> 6;
    int lane = rem & 63;
    int n  = nf * 16 + (lane & 15);
    int kb = kt * 32 + ((lane >> 4) << 3);
    short8v hi, lo;
#pragma unroll
    for (int j = 0; j < 8; ++j) {
        int k = kb + j;
        float v = (k < K && n < ncols) ? W[(size_t)k * ncols + n] : 0.f;
        unsigned short h = f2bf(v);
        hi[j] = (short)h;
        lo[j] = (short)f2bf(v - bf2f(h));
    }
    *(short8v*)(wfh + (size_t)tid * 8) = hi;
    *(short8v*)(wfl + (size_t)tid * 8) = lo;
}

// ---------------- prep1: [converts | hist] block-role-split ----------------
#define CVT_BLKS 53
__global__ __launch_bounds__(256)
void prep1(const float* __restrict__ W1,  unsigned short* w1fh, unsigned short* w1fl,
           const float* __restrict__ W2,  unsigned short* w2fh, unsigned short* w2fl,
           const float* __restrict__ Wf1, unsigned short* wf1h, unsigned short* wf1l,
           const float* __restrict__ Wf2, unsigned short* wf2h, unsigned short* wf2l,
           const float* __restrict__ Wf3, unsigned short* wf3h, unsigned short* wf3l,
           const int* __restrict__ dst, int* __restrict__ counts, int E) {
    int b = blockIdx.x;
    int t = threadIdx.x;
    if (b >= CVT_BLKS) {
        int e = (b - CVT_BLKS) * 256 + t;
        if (e < E) atomicAdd(&counts[dst[e]], 1);
        return;
    }
    if (b < 46)       convert_body(W1,  N_FEAT, 64, 4, b * 256 + t,        NKT1 * 4 * 64, w1fh, w1fl);
    else if (b < 48)  convert_body(W2,  64, 64,   4, (b - 46) * 256 + t,   2 * 4 * 64,    w2fh, w2fl);
    else if (b < 50)  convert_body(Wf1, 64, 64,   4, (b - 48) * 256 + t,   2 * 4 * 64,    wf1h, wf1l);
    else if (b < 52)  convert_body(Wf2, 64, 64,   4, (b - 50) * 256 + t,   2 * 4 * 64,    wf2h, wf2l);
    else              convert_body(Wf3, 64, NCLS, 1, (b - 52) * 256 + t,   2 * 1 * 64,    wf3h, wf3l);
}

// ---------------- 3-phase parallel exclusive scan (p1 fuses dinv) ----------------
__global__ __launch_bounds__(SCAN_BLK)
void scan_p1d(const int* __restrict__ counts, int* __restrict__ local_ex,
              int* __restrict__ blocksum, float* __restrict__ dinv, int n) {
    __shared__ int sh[SCAN_BLK];
    int t = threadIdx.x;
    int i = blockIdx.x * SCAN_BLK + t;
    int v = (i < n) ? counts[i] : 0;
    if (i < n) dinv[i] = rsqrtf((float)(v + 1));   // +1 = self loop
    sh[t] = v;
    __syncthreads();
    for (int off = 1; off < SCAN_BLK; off <<= 1) {
        int u = (t >= off) ? sh[t - off] : 0;
        __syncthreads();
        sh[t] += u;
        __syncthreads();
    }
    if (i < n) local_ex[i] = sh[t] - v;      // exclusive
    if (t == SCAN_BLK - 1) blocksum[blockIdx.x] = sh[t];
}

__global__ __launch_bounds__(128)
void scan_p2(int* __restrict__ blocksum, int* __restrict__ blockoff,
             int* __restrict__ offsets_last, int nb) {
    __shared__ int sh[128];
    int t = threadIdx.x;
    int v = (t < nb) ? blocksum[t] : 0;
    sh[t] = v;
    __syncthreads();
    for (int off = 1; off < 128; off <<= 1) {
        int u = (t >= off) ? sh[t - off] : 0;
        __syncthreads();
        sh[t] += u;
        __syncthreads();
    }
    if (t < nb) blockoff[t] = sh[t] - v;
    if (t == nb - 1) *offsets_last = sh[t];
}

__global__ __launch_bounds__(SCAN_BLK)
void scan_p3(const int* __restrict__ local_ex, const int* __restrict__ blockoff,
             int* __restrict__ offsets, int* __restrict__ cursor, int n) {
    int i = blockIdx.x * SCAN_BLK + threadIdx.x;
    if (i < n) {
        int v = local_ex[i] + blockoff[blockIdx.x];
        offsets[i] = v;
        cursor[i]  = v;
    }
}

// masked tail fragment load
__device__ __forceinline__ short8v load_frag_f32(const float* __restrict__ row, int kk) {
    float v[8];
#pragma unroll
    for (int j = 0; j < 8; ++j) v[j] = (kk + j < N_FEAT) ? row[kk + j] : 0.f;
    return cvt8(v);
}

// ---------------- GEMM1 body v10: wave-private LDS staging, contiguous A reads ----------------
// Per K-step(64) the wave stages its 32 rows x 256B: one global_load_lds per row
// (64 lanes x 4B = 256B contiguous -> the proven streaming pattern). XOR swizzle
// applied to the GLOBAL column (both-sides rule): col ^= (row&7)<<2.
__device__ __forceinline__
void gemm_xw_body(int blk, const float* __restrict__ X,
                  const unsigned short* __restrict__ wfh,
                  unsigned short* __restrict__ H16, int M, char* smem) {
    const int t    = threadIdx.x;
    const int lane = t & 63;
    const int w    = t >> 6;
    const int m0   = blk * 128 + w * 32;
    const int lrow = lane & 15;
    char* sw = smem + w * 8192;

    f32x4 acc[2][4];
#pragma unroll
    for (int i = 0; i < 2; ++i)
#pragma unroll
        for (int j = 0; j < 4; ++j) acc[i][j] = (f32x4){0.f, 0.f, 0.f, 0.f};

    const short8v* bh = (const short8v*)wfh + lane;   // + (kt*4+nf)*64
    const bool safe = (m0 + 31 < M);                  // wave-uniform

    const float* cb[8];
#pragma unroll
    for (int j = 0; j < 8; ++j)
        cb[j] = X + (size_t)m0 * N_FEAT + (lane ^ (j << 2));

#pragma unroll 2
    for (int s = 0; s < 22; ++s) {
        const int k0 = s * 64;
        // ---- stage 32 rows x 64 cols (swizzled source, linear LDS dest) ----
        if (safe) {
#pragma unroll
            for (int i = 0; i < 32; ++i)
                gl_lds4(cb[i & 7] + (size_t)i * N_FEAT + k0, sw + i * 256);
        } else {
#pragma unroll
            for (int i = 0; i < 32; ++i) {
                const float* g = X + (size_t)min(m0 + i, M - 1) * N_FEAT + k0
                               + (lane ^ ((i & 7) << 2));
                gl_lds4(g, sw + i * 256);
            }
        }
        // ---- B fragments for both kt (issued before the drain) ----
        short8v bH[2][4];
#pragma unroll
        for (int kt = 0; kt < 2; ++kt)
#pragma unroll
            for (int nf = 0; nf < 4; ++nf)
                bH[kt][nf] = bh[((s * 2 + kt) * 4 + nf) * 64];
        asm volatile("s_waitcnt vmcnt(0)" ::: "memory");
        // ---- compute ----
#pragma unroll
        for (int kt = 0; kt < 2; ++kt) {
            short8v aH[2];
#pragma unroll
            for (int mf = 0; mf < 2; ++mf) {
                int r  = mf * 16 + lrow;
                int rb = r * 256;
                int u0 = kt * 128 + ((lane >> 4) << 5);
                float v[8];
                __builtin_memcpy(v,     sw + rb + ((u0     ) ^ ((r & 7) << 4)), 16);
                __builtin_memcpy(v + 4, sw + rb + ((u0 + 16) ^ ((r & 7) << 4)), 16);
                aH[mf] = cvt8(v);
            }
#pragma unroll
            for (int mf = 0; mf < 2; ++mf)
#pragma unroll
                for (int nf = 0; nf < 4; ++nf)
                    acc[mf][nf] = __builtin_amdgcn_mfma_f32_16x16x32_bf16(aH[mf], bH[kt][nf], acc[mf][nf], 0, 0, 0);
        }
    }
    {   // tail kt=44 (cols 1408..1439, masked >= 1433) — direct from global
        const int kt = 44;
        const int koff = (lane >> 4) * 8;
        int kk = kt * 32 + koff;
        const float* a0 = X + (size_t)min(m0 + lrow,      M - 1) * N_FEAT;
        const float* a1 = X + (size_t)min(m0 + 16 + lrow, M - 1) * N_FEAT;
        short8v aH[2], bT[4];
        aH[0] = load_frag_f32(a0, kk);
        aH[1] = load_frag_f32(a1, kk);
#pragma unroll
        for (int nf = 0; nf < 4; ++nf)
            bT[nf] = bh[(kt * 4 + nf) * 64];
#pragma unroll
        for (int mf = 0; mf < 2; ++mf)
#pragma unroll
            for (int nf = 0; nf < 4; ++nf)
                acc[mf][nf] = __builtin_amdgcn_mfma_f32_16x16x32_bf16(aH[mf], bT[nf], acc[mf][nf], 0, 0, 0);
    }
    // C: col = lane&15, row = (lane>>4)*4 + reg
#pragma unroll
    for (int mf = 0; mf < 2; ++mf)
#pragma unroll
        for (int r = 0; r < 4; ++r) {
            int row = m0 + mf * 16 + ((lane >> 4) << 2) + r;
            if (row < M) {
#pragma unroll
                for (int nf = 0; nf < 4; ++nf)
                    H16[(size_t)row * 64 + nf * 16 + lrow] = f2bf(acc[mf][nf][r]);
            }
        }
}

// ---------------- scatter body: single int2 payload (src, weight) ----------------
__device__ __forceinline__
void scatter_body(int blk, const int* __restrict__ src, const int* __restrict__ dst,
                  const float* __restrict__ dinv, int* __restrict__ cursor,
                  int2* __restrict__ pay, int E) {
    int e = blk * 256 + threadIdx.x;
    if (e >= E) return;
    int s = src[e], d = dst[e];
    int pos = atomicAdd(&cursor[d], 1);
    pay[pos] = make_int2(s, __float_as_int(dinv[s] * dinv[d]));
}

// ---------------- mega2: [gemm | scatter] block-role-split ----------------
__global__ __launch_bounds__(256)
void mega2(const float* __restrict__ X, const unsigned short* __restrict__ w1fh,
           unsigned short* __restrict__ H16, int M, int GB,
           const int* __restrict__ src, const int* __restrict__ dst,
           const float* __restrict__ dinv, int* __restrict__ cursor,
           int2* __restrict__ pay, int E) {
    __shared__ __align__(16) char smem[32768];
    int b = blockIdx.x;
    if (b < GB) gemm_xw_body(b, X, w1fh, H16, M, smem);
    else        scatter_body(b - GB, src, dst, dinv, cursor, pay, E);
}

// ---------------- GEMM2 v3: [M,64] f32 @ [64,64], cvt_pk, frag-major W2 hi/lo ----------------
__global__ __launch_bounds__(256)
void gemm_hid_v3(const float* __restrict__ A,
                 const unsigned short* __restrict__ wfh,
                 const unsigned short* __restrict__ wfl,
                 unsigned short* __restrict__ H16, int M) {
    const int t    = threadIdx.x;
    const int lane = t & 63;
    const int w    = t >> 6;
    const int m0   = blockIdx.x * 128 + w * 32;
    const int lrow = lane & 15;
    const int koff = (lane >> 4) * 8;

    f32x4 acc[2][4];
#pragma unroll
    for (int i = 0; i < 2; ++i)
#pragma unroll
        for (int j = 0; j < 4; ++j) acc[i][j] = (f32x4){0.f, 0.f, 0.f, 0.f};

    const float* a0 = A + (size_t)min(m0 + lrow,      M - 1) * 64;
    const float* a1 = A + (size_t)min(m0 + 16 + lrow, M - 1) * 64;
    const short8v* bh = (const short8v*)wfh + lane;
    const short8v* bl = (const short8v*)wfl + lane;

#pragma unroll
    for (int kt = 0; kt < 2; ++kt) {
        int kk = kt * 32 + koff;
        short8v aH[2], bH[4], bL[4];
        float v0[8], v1[8];
        __builtin_memcpy(v0, a0 + kk, 32);
        __builtin_memcpy(v1, a1 + kk, 32);
        aH[0] = cvt8(v0);
        aH[1] = cvt8(v1);
#pragma unroll
        for (int nf = 0; nf < 4; ++nf) {
            bH[nf] = bh[(kt * 4 + nf) * 64];
            bL[nf] = bl[(kt * 4 + nf) * 64];
        }
#pragma unroll
        for (int mf = 0; mf < 2; ++mf)
#pragma unroll
            for (int nf = 0; nf < 4; ++nf) {
                acc[mf][nf] = __builtin_amdgcn_mfma_f32_16x16x32_bf16(aH[mf], bH[nf], acc[mf][nf], 0, 0, 0);
                acc[mf][nf] = __builtin_amdgcn_mfma_f32_16x16x32_bf16(aH[mf], bL[nf], acc[mf][nf], 0, 0, 0);
            }
    }
#pragma unroll
    for (int mf = 0; mf < 2; ++mf)
#pragma unroll
        for (int r = 0; r < 4; ++r) {
            int row = m0 + mf * 16 + ((lane >> 4) << 2) + r;
            if (row < M) {
#pragma unroll
                for (int nf = 0; nf < 4; ++nf)
                    H16[(size_t)row * 64 + nf * 16 + lrow] = f2bf(acc[mf][nf][r]);
            }
        }
}

// ---------------- aggregate v4: 8 edges/iter, 2 gathers in flight ----------------
__global__ __launch_bounds__(256)
void aggregate_v4(const unsigned short* __restrict__ h16, const int2* __restrict__ pay,
                  const int* __restrict__ offsets,
                  const float* __restrict__ dinv, const float* __restrict__ bias,
                  float* __restrict__ out, int n) {
    int wid  = (blockIdx.x * blockDim.x + threadIdx.x) >> 6;
    int lane = threadIdx.x & 63;
    if (wid >= n) return;
    const int g  = lane >> 4;          // edge subgroup 0..3
    const int f4 = (lane & 15) * 4;    // feature base

    float a0 = 0.f, a1 = 0.f, a2 = 0.f, a3 = 0.f;
    int beg = offsets[wid], end = offsets[wid + 1];
    int cnt = end - beg;
    int nq  = cnt >> 3;
    int e   = beg + g;
#pragma unroll 2
    for (int q = 0; q < nq; ++q, e += 8) {
        int2 p1 = pay[e];
        int2 p2 = pay[e + 4];
        float w1 = __int_as_float(p1.y);
        float w2 = __int_as_float(p2.y);
        ushort4 h1 = *(const ushort4*)(h16 + (size_t)p1.x * HID + f4);
        ushort4 h2 = *(const ushort4*)(h16 + (size_t)p2.x * HID + f4);
        a0 = fmaf(bf2f(h1.x), w1, a0); a1 = fmaf(bf2f(h1.y), w1, a1);
        a2 = fmaf(bf2f(h1.z), w1, a2); a3 = fmaf(bf2f(h1.w), w1, a3);
        a0 = fmaf(bf2f(h2.x), w2, a0); a1 = fmaf(bf2f(h2.y), w2, a1);
        a2 = fmaf(bf2f(h2.z), w2, a2); a3 = fmaf(bf2f(h2.w), w2, a3);
    }
    int rem  = cnt & 7;
    int base = beg + nq * 8;
    if (g < rem) {
        int2  pw  = pay[base + g];
        float wgt = __int_as_float(pw.y);
        ushort4 hv = *(const ushort4*)(h16 + (size_t)pw.x * HID + f4);
        a0 = fmaf(bf2f(hv.x), wgt, a0); a1 = fmaf(bf2f(hv.y), wgt, a1);
        a2 = fmaf(bf2f(hv.z), wgt, a2); a3 = fmaf(bf2f(hv.w), wgt, a3);
    }
    if (g + 4 < rem) {
        int2  pw  = pay[base + g + 4];
        float wgt = __int_as_float(pw.y);
        ushort4 hv = *(const ushort4*)(h16 + (size_t)pw.x * HID + f4);
        a0 = fmaf(bf2f(hv.x), wgt, a0); a1 = fmaf(bf2f(hv.y), wgt, a1);
        a2 = fmaf(bf2f(hv.z), wgt, a2); a3 = fmaf(bf2f(hv.w), wgt, a3);
    }
    if (g == 0) {   // self loop
        float di = dinv[wid];
        float w2 = di * di;
        ushort4 hv = *(const ushort4*)(h16 + (size_t)wid * HID + f4);
        a0 = fmaf(bf2f(hv.x), w2, a0); a1 = fmaf(bf2f(hv.y), w2, a1);
        a2 = fmaf(bf2f(hv.z), w2, a2); a3 = fmaf(bf2f(hv.w), w2, a3);
    }
    a0 += __shfl_xor(a0, 16); a0 += __shfl_xor(a0, 32);
    a1 += __shfl_xor(a1, 16); a1 += __shfl_xor(a1, 32);
    a2 += __shfl_xor(a2, 16); a2 += __shfl_xor(a2, 32);
    a3 += __shfl_xor(a3, 16); a3 += __shfl_xor(a3, 32);
    if (g == 0) {
        float4 bv = *(const float4*)&bias[f4];
        float4 o;
        o.x = fmaxf(a0 + bv.x, 0.f);
        o.y = fmaxf(a1 + bv.y, 0.f);
        o.z = fmaxf(a2 + bv.z, 0.f);
        o.w = fmaxf(a3 + bv.w, 0.f);
        *(float4*)&out[(size_t)wid * HID + f4] = o;
    }
}

// ---------------- fused MLP head via MFMA + butterfly log_softmax ----------------
__device__ __forceinline__ void split8(const float* v, short8v& h, short8v& l) {
    h = cvt8(v);
    float res[8];
#pragma unroll
    for (int j = 0; j < 8; ++j) res[j] = v[j] - bf2f((unsigned short)h[j]);
    l = cvt8(res);
}

__global__ __launch_bounds__(256)
void mlp_mfma(const float* __restrict__ y,
              const unsigned short* __restrict__ w1h, const unsigned short* __restrict__ w1l,
              const unsigned short* __restrict__ w2h, const unsigned short* __restrict__ w2l,
              const unsigned short* __restrict__ w3h, const unsigned short* __restrict__ w3l,
              const float* __restrict__ bf1, const float* __restrict__ bf2,
              const float* __restrict__ bf3,
              float* __restrict__ out, int M) {
    __shared__ float tbuf[4][32 * 64];
    const int t    = threadIdx.x;
    const int lane = t & 63;
    const int w    = t >> 6;
    const int m0   = blockIdx.x * 128 + w * 32;
    const int lrow = lane & 15;
    const int hi16 = lane >> 4;
    const int koff = hi16 * 8;
    float* tb = tbuf[w];

    float b1v[4], b2v[4];
#pragma unroll
    for (int nf = 0; nf < 4; ++nf) {
        b1v[nf] = bf1[nf * 16 + lrow];
        b2v[nf] = bf2[nf * 16 + lrow];
    }
    float b3v = (lrow < NCLS) ? bf3[lrow] : 0.f;

    short8v aH[2][2], aL[2][2];   // [mf][kt]
    {
        const float* a0 = y + (size_t)min(m0 + lrow,      M - 1) * 64;
        const float* a1 = y + (size_t)min(m0 + 16 + lrow, M - 1) * 64;
#pragma unroll
        for (int kt = 0; kt < 2; ++kt) {
            float v0[8], v1[8];
            __builtin_memcpy(v0, a0 + kt * 32 + koff, 32);
            __builtin_memcpy(v1, a1 + kt * 32 + koff, 32);
            split8(v0, aH[0][kt], aL[0][kt]);
            split8(v1, aH[1][kt], aL[1][kt]);
        }
    }

#pragma unroll
    for (int layer = 0; layer < 2; ++layer) {
        const unsigned short* wh = layer ? w2h : w1h;
        const unsigned short* wl = layer ? w2l : w1l;
        const float* bv = layer ? b2v : b1v;
        f32x4 acc[2][4];
#pragma unroll
        for (int i = 0; i < 2; ++i)
#pragma unroll
            for (int j = 0; j < 4; ++j) acc[i][j] = (f32x4){0.f, 0.f, 0.f, 0.f};
#pragma unroll
        for (int kt = 0; kt < 2; ++kt) {
            short8v bH[4], bL[4];
#pragma unroll
            for (int nf = 0; nf < 4; ++nf) {
                bH[nf] = *((const short8v*)wh + (kt * 4 + nf) * 64 + lane);
                bL[nf] = *((const short8v*)wl + (kt * 4 + nf) * 64 + lane);
            }
#pragma unroll
            for (int mf = 0; mf < 2; ++mf)
#pragma unroll
                for (int nf = 0; nf < 4; ++nf) {
                    acc[mf][nf] = __builtin_amdgcn_mfma_f32_16x16x32_bf16(aH[mf][kt], bH[nf], acc[mf][nf], 0, 0, 0);
                    acc[mf][nf] = __builtin_amdgcn_mfma_f32_16x16x32_bf16(aH[mf][kt], bL[nf], acc[mf][nf], 0, 0, 0);
                    acc[mf][nf] = __builtin_amdgcn_mfma_f32_16x16x32_bf16(aL[mf][kt], bH[nf], acc[mf][nf], 0, 0, 0);
                }
        }
#pragma unroll
        for (int mf = 0; mf < 2; ++mf)
#pragma unroll
            for (int nf = 0; nf < 4; ++nf)
#pragma unroll
                for (int r = 0; r < 4; ++r) {
                    int row = mf * 16 + hi16 * 4 + r;
                    int col = nf * 16 + lrow;
                    float v = fmaxf(acc[mf][nf][r] + bv[nf], 0.f);
                    *(float*)((char*)tb + ((((row << 6) + col) << 2) ^ ((row & 3) << 5))) = v;
                }
#pragma unroll
        for (int mf = 0; mf < 2; ++mf)
#pragma unroll
            for (int kt = 0; kt < 2; ++kt) {
                int row = mf * 16 + lrow;
                float v[8];
                __builtin_memcpy(v, (char*)tb + ((((row << 6) + kt * 32 + koff) << 2) ^ ((row & 3) << 5)), 32);
                split8(v, aH[mf][kt], aL[mf][kt]);
            }
    }

    f32x4 acc3[2];
    acc3[0] = (f32x4){0.f, 0.f, 0.f, 0.f};
    acc3[1] = (f32x4){0.f, 0.f, 0.f, 0.f};
#pragma unroll
    for (int kt = 0; kt < 2; ++kt) {
        short8v bH = *((const short8v*)w3h + kt * 64 + lane);
        short8v bL = *((const short8v*)w3l + kt * 64 + lane);
#pragma unroll
        for (int mf = 0; mf < 2; ++mf) {
            acc3[mf] = __builtin_amdgcn_mfma_f32_16x16x32_bf16(aH[mf][kt], bH, acc3[mf], 0, 0, 0);
            acc3[mf] = __builtin_amdgcn_mfma_f32_16x16x32_bf16(aH[mf][kt], bL, acc3[mf], 0, 0, 0);
            acc3[mf] = __builtin_amdgcn_mfma_f32_16x16x32_bf16(aL[mf][kt], bH, acc3[mf], 0, 0, 0);
        }
    }
#pragma unroll
    for (int mf = 0; mf < 2; ++mf)
#pragma unroll
        for (int r = 0; r < 4; ++r) {
            float z  = acc3[mf][r] + b3v;
            float zm = (lrow < NCLS) ? z : -1e30f;
            float m  = zm;
#pragma unroll
            for (int mask = 1; mask < 16; mask <<= 1)
                m = fmaxf(m, __shfl_xor(m, mask));
            float ev = (lrow < NCLS) ? expf(z - m) : 0.f;
            float ss = ev;
#pragma unroll
            for (int mask = 1; mask < 16; mask <<= 1)
                ss += __shfl_xor(ss, mask);
            float res = z - (m + logf(ss));
            int row = m0 + mf * 16 + hi16 * 4 + r;
            if (row < M && lrow < NCLS)
                out[(size_t)row * NCLS + lrow] = res;
        }
}

extern "C" void kernel_launch(void* const* d_in, const int* in_sizes, int n_in,
                              void* d_out, int out_size, void* d_ws, size_t ws_size,
                              hipStream_t stream) {
    const float* x   = (const float*)d_in[0];
    const int*   ei  = (const int*)d_in[1];
    const float* W1  = (const float*)d_in[2];
    const float* b1  = (const float*)d_in[3];
    const float* W2  = (const float*)d_in[4];
    const float* b2  = (const float*)d_in[5];
    const float* Wf1 = (const float*)d_in[6];
    const float* bf1 = (const float*)d_in[7];
    const float* Wf2 = (const float*)d_in[8];
    const float* bf2 = (const float*)d_in[9];
    const float* Wf3 = (const float*)d_in[10];
    const float* bf3 = (const float*)d_in[11];

    const int N = N_NODES;
    const int E = in_sizes[1] / 2;
    float* outp = (float*)d_out;

    char* p = (char*)d_ws;
    auto alloc = [&](size_t bytes) {
        char* q = p;
        p += (bytes + 255) & ~(size_t)255;
        return q;
    };
    int*            counts   = (int*)           alloc((size_t)N * 4);
    int*            offsets  = (int*)           alloc((size_t)(N + 1) * 4);
    int*            cursor   = (int*)           alloc((size_t)N * 4);
    int*            local_ex = (int*)           alloc((size_t)N * 4);
    int*            blocksum = (int*)           alloc((size_t)NBLK * 4);
    int*            blockoff = (int*)           alloc((size_t)NBLK * 4);
    float*          dinv     = (float*)         alloc((size_t)N * 4);
    int2*           pay      = (int2*)          alloc((size_t)E * 8);
    unsigned short* w1fh     = (unsigned short*)alloc((size_t)NKT1 * 4 * 64 * 8 * 2);
    unsigned short* w1fl     = (unsigned short*)alloc((size_t)NKT1 * 4 * 64 * 8 * 2);
    unsigned short* w2fh     = (unsigned short*)alloc((size_t)2 * 4 * 64 * 8 * 2);
    unsigned short* w2fl     = (unsigned short*)alloc((size_t)2 * 4 * 64 * 8 * 2);
    unsigned short* wf1h     = (unsigned short*)alloc((size_t)2 * 4 * 64 * 8 * 2);
    unsigned short* wf1l     = (unsigned short*)alloc((size_t)2 * 4 * 64 * 8 * 2);
    unsigned short* wf2h     = (unsigned short*)alloc((size_t)2 * 4 * 64 * 8 * 2);
    unsigned short* wf2l     = (unsigned short*)alloc((size_t)2 * 4 * 64 * 8 * 2);
    unsigned short* wf3h     = (unsigned short*)alloc((size_t)2 * 1 * 64 * 8 * 2);
    unsigned short* wf3l     = (unsigned short*)alloc((size_t)2 * 1 * 64 * 8 * 2);
    unsigned short* bufH16   = (unsigned short*)alloc((size_t)N * HID * 2);
    float*          bufF     = (float*)         alloc((size_t)N * HID * 4);

    const int* src = ei;
    const int* dst = ei + E;

    hipMemsetAsync(counts, 0, (size_t)N * 4, stream);
    int ge = (E + 255) / 256;     // 12500 hist/scatter blocks
    int GB = (N + 127) / 128;     // 782 gemm blocks

    // [converts | hist]
    prep1<<<CVT_BLKS + ge, 256, 0, stream>>>(W1, w1fh, w1fl, W2, w2fh, w2fl,
                                             Wf1, wf1h, wf1l, Wf2, wf2h, wf2l,
                                             Wf3, wf3h, wf3l, dst, counts, E);
    scan_p1d<<<NBLK, SCAN_BLK, 0, stream>>>(counts, local_ex, blocksum, dinv, N);
    scan_p2<<<1, 128, 0, stream>>>(blocksum, blockoff, &offsets[N], NBLK);
    scan_p3<<<NBLK, SCAN_BLK, 0, stream>>>(local_ex, blockoff, offsets, cursor, N);

    // [gemm layer1 | scatter]
    mega2<<<GB + ge, 256, 0, stream>>>(x, w1fh, bufH16, N, GB,
                                       src, dst, dinv, cursor, pay, E);

    aggregate_v4<<<(N + 3) / 4, 256, 0, stream>>>(bufH16, pay, offsets, dinv, b1, bufF, N);
    gemm_hid_v3<<<(N + 127) / 128, 256, 0, stream>>>(bufF, w2fh, w2fl, bufH16, N);
    aggregate_v4<<<(N + 3) / 4, 256, 0, stream>>>(bufH16, pay, offsets, dinv, b2, bufF, N);
    mlp_mfma<<<(N + 127) / 128, 256, 0, stream>>>(bufF, wf1h, wf1l, wf2h, wf2l, wf3h, wf3l,
                                                  bf1, bf2, bf3, outp, N);
}